// Round 2
// baseline (499.573 us; speedup 1.0000x reference)
//
#include <hip/hip_runtime.h>
#include <hip/hip_bf16.h>
#include <cstdint>

#define S_LEN 4096
#define NHEAD 4
#define HDIM 32
#define HID 128
#define CBATCH 4
#define EPSW 1e-8f
#define NSPLIT 2
#define KCHUNK (S_LEN / NSPLIT)

typedef __attribute__((ext_vector_type(8))) short short8v;
typedef __attribute__((ext_vector_type(4))) float float4v;

__device__ __forceinline__ unsigned short f2bf(float f) {
    unsigned int u = __float_as_uint(f);
    return (unsigned short)((u + 0x7fffu + ((u >> 16) & 1u)) >> 16);
}

__device__ __forceinline__ float exp2_asm(float x) {
    float r;
    asm("v_exp_f32 %0, %1" : "=v"(r) : "v"(x));
    return r;
}

__device__ __forceinline__ unsigned cvt_pk_bf16(float lo, float hi) {
    unsigned r;
    asm("v_cvt_pk_bf16_f32 %0, %1, %2" : "=v"(r) : "v"(lo), "v"(hi));
    return r;
}

// ---------------------------------------------------------------------------
// Kernel 1: fused QKV projection.  out = (x @ W.T + b) [* SCALE*log2e for Q]
// ---------------------------------------------------------------------------
__global__ __launch_bounds__(256) void qkv_proj_kernel(
    const float* __restrict__ x,
    const float* __restrict__ Wq, const float* __restrict__ bq,
    const float* __restrict__ Wk, const float* __restrict__ bk,
    const float* __restrict__ Wv, const float* __restrict__ bv,
    unsigned short* __restrict__ Qo, unsigned short* __restrict__ Ko,
    unsigned short* __restrict__ Vo)
{
    __shared__ float xs[64][132];
    __shared__ float wsT[64][68];

    const int tid = threadIdx.x;
    const int mrow0 = blockIdx.x * 64;
    const int n0 = blockIdx.y * 64;
    const int p = blockIdx.z;
    const float* W    = (p == 0) ? Wq : (p == 1) ? Wk : Wv;
    const float* bias = (p == 0) ? bq : (p == 1) ? bk : bv;
    unsigned short* Out = (p == 0) ? Qo : (p == 1) ? Ko : Vo;

    for (int i = tid; i < 64 * 32; i += 256) {
        int r = i >> 5, c4 = (i & 31) * 4;
        *(float4*)&xs[r][c4] = *(const float4*)&x[(size_t)(mrow0 + r) * HID + c4];
    }

    float acc[4][4] = {};
    const int tr = tid >> 4;
    const int tc = tid & 15;

    for (int ph = 0; ph < 2; ++ph) {
        __syncthreads();
        for (int i = tid; i < 64 * 16; i += 256) {
            int r = i >> 4, c4 = (i & 15) * 4;
            float4 wv = *(const float4*)&W[(size_t)(n0 + r) * HID + ph * 64 + c4];
            wsT[c4 + 0][r] = wv.x;
            wsT[c4 + 1][r] = wv.y;
            wsT[c4 + 2][r] = wv.z;
            wsT[c4 + 3][r] = wv.w;
        }
        __syncthreads();
        #pragma unroll 4
        for (int k4 = 0; k4 < 16; ++k4) {
            float4 xv[4];
            #pragma unroll
            for (int i = 0; i < 4; ++i)
                xv[i] = *(const float4*)&xs[tr * 4 + i][ph * 64 + k4 * 4];
            #pragma unroll
            for (int kk = 0; kk < 4; ++kk) {
                float4 wv = *(const float4*)&wsT[k4 * 4 + kk][tc * 4];
                #pragma unroll
                for (int i = 0; i < 4; ++i) {
                    float xk = ((const float*)&xv[i])[kk];
                    acc[i][0] += xk * wv.x;
                    acc[i][1] += xk * wv.y;
                    acc[i][2] += xk * wv.z;
                    acc[i][3] += xk * wv.w;
                }
            }
        }
    }

    // SCALE * log2(e): exp(s*SCALE) == exp2(s * SCALE * log2e)
    const float scale = (p == 0) ? 0.25500544458521289f : 1.0f;
    float4 bv4 = *(const float4*)&bias[n0 + tc * 4];
    const int nbase = n0 + tc * 4;
    const int h = nbase >> 5;
    const int d = nbase & 31;
    #pragma unroll
    for (int i = 0; i < 4; ++i) {
        int m = mrow0 + tr * 4 + i;
        int c = m >> 12, s = m & 4095;
        unsigned short pk[4];
        pk[0] = f2bf((acc[i][0] + bv4.x) * scale);
        pk[1] = f2bf((acc[i][1] + bv4.y) * scale);
        pk[2] = f2bf((acc[i][2] + bv4.z) * scale);
        pk[3] = f2bf((acc[i][3] + bv4.w) * scale);
        *(uint2*)&Out[((size_t)(c * NHEAD + h) * S_LEN + s) * HDIM + d] = *(uint2*)pk;
    }
}

// ---------------------------------------------------------------------------
// Kernel 2: transpose V (C,NH,S,HD) -> Vt (C,NH,HD,S), bf16.
// ---------------------------------------------------------------------------
__global__ __launch_bounds__(256) void vtrans_kernel(
    const unsigned short* __restrict__ V, unsigned short* __restrict__ Vt)
{
    __shared__ unsigned short vs[64][40];
    const int tid = threadIdx.x;
    const int chh = blockIdx.y;
    const int s0 = blockIdx.x * 64;
    const size_t base = (size_t)chh * S_LEN * HDIM;
    {
        int r = tid >> 2, ch = (tid & 3) * 8;
        *(uint4*)&vs[r][ch] = *(const uint4*)&V[base + (size_t)(s0 + r) * HDIM + ch];
    }
    __syncthreads();
    {
        int dd = tid >> 3, chs = (tid & 7) * 8;
        unsigned short pk[8];
        #pragma unroll
        for (int j = 0; j < 8; ++j) pk[j] = vs[chs + j][dd];
        *(uint4*)&Vt[(size_t)chh * HDIM * S_LEN + (size_t)dd * S_LEN + s0 + chs] = *(uint4*)pk;
    }
}

// ---------------------------------------------------------------------------
// Kernel 3: attention, split-K.  Block = (16-query tile, c, split); wave=head.
// p = max(ew,eps) * exp2(qk_scaled); denom accumulated via ones-MFMA.
// Writes unnormalized partial O and per-split denominator.
// ---------------------------------------------------------------------------
__global__ __launch_bounds__(256) void attn_kernel(
    const unsigned short* __restrict__ Q, const unsigned short* __restrict__ K,
    const unsigned short* __restrict__ Vt, const float* __restrict__ ew,
    float* __restrict__ partO, float* __restrict__ den)
{
    const int tid = threadIdx.x;
    const int w = tid >> 6;          // head
    const int lane = tid & 63;
    const int li = lane & 15;
    const int g = lane >> 4;
    const int c = blockIdx.y;
    const int qbase = blockIdx.x * 16;
    const int split = blockIdx.z;
    const int kb0 = split * KCHUNK;

    const size_t hb = (size_t)(c * NHEAD + w) * S_LEN * HDIM;
    const unsigned short* Qh = Q + hb;
    const unsigned short* Kh = K + hb;

    short8v qf = *(const short8v*)&Qh[(size_t)(qbase + li) * HDIM + g * 8];

    short8v ones;
    #pragma unroll
    for (int j = 0; j < 8; ++j) ones[j] = (short)0x3F80;  // bf16 1.0

    // incrementing pointers
    const unsigned short* kp0 = Kh + (size_t)(kb0 + li) * HDIM + g * 8;
    const unsigned short* kp1 = kp0 + (size_t)16 * HDIM;
    const unsigned short* vp0 = Vt + hb + (size_t)li * S_LEN + kb0 + g * 4;
    const unsigned short* vp1 = vp0 + (size_t)16 * S_LEN;
    const float* ep = ew + (size_t)c * S_LEN * S_LEN + (size_t)(qbase + li) * S_LEN + kb0 + g * 4;

    float4v oacc[2] = {};
    float4v dacc = {};
    const float4v zero4 = {0.f, 0.f, 0.f, 0.f};

    for (int it = 0; it < KCHUNK / 32; ++it) {
        short8v kf0 = *(const short8v*)kp0;
        short8v kf1 = *(const short8v*)kp1;

        union { short8v v; uint2 u2[2]; } v0, v1;
        v0.u2[0] = *(const uint2*)vp0;
        v0.u2[1] = *(const uint2*)(vp0 + 16);
        v1.u2[0] = *(const uint2*)vp1;
        v1.u2[1] = *(const uint2*)(vp1 + 16);

        float4 e0 = *(const float4*)ep;
        float4 e1 = *(const float4*)(ep + 16);

        float4v s0 = __builtin_amdgcn_mfma_f32_16x16x32_bf16(kf0, qf, zero4, 0, 0, 0);
        float4v s1 = __builtin_amdgcn_mfma_f32_16x16x32_bf16(kf1, qf, zero4, 0, 0, 0);

        float p0 = fmaxf(e0.x, EPSW) * exp2_asm(s0[0]);
        float p1 = fmaxf(e0.y, EPSW) * exp2_asm(s0[1]);
        float p2 = fmaxf(e0.z, EPSW) * exp2_asm(s0[2]);
        float p3 = fmaxf(e0.w, EPSW) * exp2_asm(s0[3]);
        float p4 = fmaxf(e1.x, EPSW) * exp2_asm(s1[0]);
        float p5 = fmaxf(e1.y, EPSW) * exp2_asm(s1[1]);
        float p6 = fmaxf(e1.z, EPSW) * exp2_asm(s1[2]);
        float p7 = fmaxf(e1.w, EPSW) * exp2_asm(s1[3]);

        union { short8v v; unsigned u[4]; } pu;
        pu.u[0] = cvt_pk_bf16(p0, p1);
        pu.u[1] = cvt_pk_bf16(p2, p3);
        pu.u[2] = cvt_pk_bf16(p4, p5);
        pu.u[3] = cvt_pk_bf16(p6, p7);

        oacc[0] = __builtin_amdgcn_mfma_f32_16x16x32_bf16(v0.v, pu.v, oacc[0], 0, 0, 0);
        oacc[1] = __builtin_amdgcn_mfma_f32_16x16x32_bf16(v1.v, pu.v, oacc[1], 0, 0, 0);
        dacc    = __builtin_amdgcn_mfma_f32_16x16x32_bf16(ones, pu.v, dacc,    0, 0, 0);

        kp0 += 32 * HDIM;
        kp1 += 32 * HDIM;
        vp0 += 32;
        vp1 += 32;
        ep  += 32;
    }

    const size_t pb = (((size_t)split * CBATCH + c) * NHEAD + w) * S_LEN + qbase + li;
    #pragma unroll
    for (int db = 0; db < 2; ++db) {
        float4 o;
        o.x = oacc[db][0];
        o.y = oacc[db][1];
        o.z = oacc[db][2];
        o.w = oacc[db][3];
        *(float4*)&partO[pb * HDIM + db * 16 + g * 4] = o;
    }
    if (g == 0) den[pb] = dacc[0];
}

// ---------------------------------------------------------------------------
// Kernel 4: combine splits -> normalized attention output (C,S,HID) fp32.
// ---------------------------------------------------------------------------
__global__ __launch_bounds__(256) void combine_kernel(
    const float* __restrict__ pO, const float* __restrict__ den,
    float* __restrict__ attnbuf)
{
    const int idx = blockIdx.x * 256 + threadIdx.x;
    const int d4 = idx & 7;
    const int q  = (idx >> 3) & (S_LEN - 1);
    const int h  = (idx >> 15) & 3;
    const int c  = idx >> 17;

    const size_t b0 = ((size_t)(0 * CBATCH + c) * NHEAD + h) * S_LEN + q;
    const size_t b1 = ((size_t)(1 * CBATCH + c) * NHEAD + h) * S_LEN + q;
    float4 a = *(const float4*)&pO[b0 * HDIM + d4 * 4];
    float4 b = *(const float4*)&pO[b1 * HDIM + d4 * 4];
    float inv = 1.0f / (den[b0] + den[b1]);
    float4 o;
    o.x = (a.x + b.x) * inv;
    o.y = (a.y + b.y) * inv;
    o.z = (a.z + b.z) * inv;
    o.w = (a.w + b.w) * inv;
    *(float4*)&attnbuf[((size_t)c * S_LEN + q) * HID + h * HDIM + d4 * 4] = o;
}

// ---------------------------------------------------------------------------
// Kernel 5: output projection. out = attnbuf @ Wo.T + bo   (all fp32)
// ---------------------------------------------------------------------------
__global__ __launch_bounds__(256) void out_proj_kernel(
    const float* __restrict__ ain, const float* __restrict__ Wo,
    const float* __restrict__ bo, float* __restrict__ out)
{
    __shared__ float xs[64][132];
    __shared__ float wsT[64][68];

    const int tid = threadIdx.x;
    const int mrow0 = blockIdx.x * 64;
    const int n0 = blockIdx.y * 64;

    for (int i = tid; i < 64 * 32; i += 256) {
        int r = i >> 5, c4 = (i & 31) * 4;
        *(float4*)&xs[r][c4] = *(const float4*)&ain[(size_t)(mrow0 + r) * HID + c4];
    }

    float acc[4][4] = {};
    const int tr = tid >> 4;
    const int tc = tid & 15;

    for (int ph = 0; ph < 2; ++ph) {
        __syncthreads();
        for (int i = tid; i < 64 * 16; i += 256) {
            int r = i >> 4, c4 = (i & 15) * 4;
            float4 wv = *(const float4*)&Wo[(size_t)(n0 + r) * HID + ph * 64 + c4];
            wsT[c4 + 0][r] = wv.x;
            wsT[c4 + 1][r] = wv.y;
            wsT[c4 + 2][r] = wv.z;
            wsT[c4 + 3][r] = wv.w;
        }
        __syncthreads();
        #pragma unroll 4
        for (int k4 = 0; k4 < 16; ++k4) {
            float4 xv[4];
            #pragma unroll
            for (int i = 0; i < 4; ++i)
                xv[i] = *(const float4*)&xs[tr * 4 + i][ph * 64 + k4 * 4];
            #pragma unroll
            for (int kk = 0; kk < 4; ++kk) {
                float4 wv = *(const float4*)&wsT[k4 * 4 + kk][tc * 4];
                #pragma unroll
                for (int i = 0; i < 4; ++i) {
                    float xk = ((const float*)&xv[i])[kk];
                    acc[i][0] += xk * wv.x;
                    acc[i][1] += xk * wv.y;
                    acc[i][2] += xk * wv.z;
                    acc[i][3] += xk * wv.w;
                }
            }
        }
    }

    float4 bv4 = *(const float4*)&bo[n0 + tc * 4];
    #pragma unroll
    for (int i = 0; i < 4; ++i) {
        int m = mrow0 + tr * 4 + i;
        float4 o;
        o.x = acc[i][0] + bv4.x;
        o.y = acc[i][1] + bv4.y;
        o.z = acc[i][2] + bv4.z;
        o.w = acc[i][3] + bv4.w;
        *(float4*)&out[(size_t)m * HID + n0 + tc * 4] = o;
    }
}

extern "C" void kernel_launch(void* const* d_in, const int* in_sizes, int n_in,
                              void* d_out, int out_size, void* d_ws, size_t ws_size,
                              hipStream_t stream) {
    const float* x  = (const float*)d_in[0];
    const float* ew = (const float*)d_in[1];
    const float* Wq = (const float*)d_in[2];
    const float* bq = (const float*)d_in[3];
    const float* Wk = (const float*)d_in[4];
    const float* bk = (const float*)d_in[5];
    const float* Wv = (const float*)d_in[6];
    const float* bv = (const float*)d_in[7];
    const float* Wo = (const float*)d_in[8];
    const float* bo = (const float*)d_in[9];
    float* out = (float*)d_out;

    char* ws = (char*)d_ws;
    const size_t QSZ = (size_t)CBATCH * NHEAD * S_LEN * HDIM * sizeof(unsigned short); // 4 MiB
    // layout (28.5 MiB total):
    //   [0, QSZ)        Qw          (attnbuf aliases [0, 8MiB) after attn)
    //   [QSZ, 2QSZ)     Kw
    //   [2QSZ, 3QSZ)    Vtw
    //   [3QSZ, 4QSZ)    Vw          (dead after vtrans; partO overlaps it)
    //   [3QSZ, 3QSZ+16M) partO
    //   [3QSZ+16M, +0.5M) den
    unsigned short* Qw  = (unsigned short*)(ws);
    unsigned short* Kw  = (unsigned short*)(ws + QSZ);
    unsigned short* Vtw = (unsigned short*)(ws + 2 * QSZ);
    unsigned short* Vw  = (unsigned short*)(ws + 3 * QSZ);
    float* partO = (float*)(ws + 3 * QSZ);
    float* den   = (float*)(ws + 3 * QSZ + (size_t)NSPLIT * CBATCH * NHEAD * S_LEN * HDIM * sizeof(float));
    float* attnbuf = (float*)(ws);

    qkv_proj_kernel<<<dim3(256, 2, 3), 256, 0, stream>>>(x, Wq, bq, Wk, bk, Wv, bv, Qw, Kw, Vw);
    vtrans_kernel<<<dim3(S_LEN / 64, CBATCH * NHEAD), 256, 0, stream>>>(Vw, Vtw);
    attn_kernel<<<dim3(S_LEN / 16, CBATCH, NSPLIT), 256, 0, stream>>>(Qw, Kw, Vtw, ew, partO, den);
    combine_kernel<<<dim3((CBATCH * S_LEN * HID / 4) / 256), 256, 0, stream>>>(partO, den, attnbuf);
    out_proj_kernel<<<dim3(256, 2), 256, 0, stream>>>(attnbuf, Wo, bo, out);
}

// Round 4
// 316.965 us; speedup vs baseline: 1.5761x; 1.5761x over previous
//
#include <hip/hip_runtime.h>
#include <hip/hip_bf16.h>
#include <cstdint>

#define S_LEN 4096
#define NHEAD 4
#define HDIM 32
#define HID 128
#define CBATCH 4
#define EPSW 1e-8f
#define NSPLIT 2
#define KCHUNK (S_LEN / NSPLIT)

typedef __attribute__((ext_vector_type(8))) short short8v;
typedef __attribute__((ext_vector_type(4))) float float4v;

__device__ __forceinline__ unsigned short f2bf(float f) {
    unsigned int u = __float_as_uint(f);
    return (unsigned short)((u + 0x7fffu + ((u >> 16) & 1u)) >> 16);
}

__device__ __forceinline__ float exp2_asm(float x) {
    float r;
    asm("v_exp_f32 %0, %1" : "=v"(r) : "v"(x));
    return r;
}

__device__ __forceinline__ unsigned cvt_pk_bf16(float lo, float hi) {
    unsigned r;
    asm("v_cvt_pk_bf16_f32 %0, %1, %2" : "=v"(r) : "v"(lo), "v"(hi));
    return r;
}

// ---------------------------------------------------------------------------
// Kernel 1: fused QKV projection.  out = (x @ W.T + b) [* SCALE*log2e for Q]
// ---------------------------------------------------------------------------
__global__ __launch_bounds__(256) void qkv_proj_kernel(
    const float* __restrict__ x,
    const float* __restrict__ Wq, const float* __restrict__ bq,
    const float* __restrict__ Wk, const float* __restrict__ bk,
    const float* __restrict__ Wv, const float* __restrict__ bv,
    unsigned short* __restrict__ Qo, unsigned short* __restrict__ Ko,
    unsigned short* __restrict__ Vo)
{
    __shared__ float xs[64][132];
    __shared__ float wsT[64][68];

    const int tid = threadIdx.x;
    const int mrow0 = blockIdx.x * 64;
    const int n0 = blockIdx.y * 64;
    const int p = blockIdx.z;
    const float* W    = (p == 0) ? Wq : (p == 1) ? Wk : Wv;
    const float* bias = (p == 0) ? bq : (p == 1) ? bk : bv;
    unsigned short* Out = (p == 0) ? Qo : (p == 1) ? Ko : Vo;

    for (int i = tid; i < 64 * 32; i += 256) {
        int r = i >> 5, c4 = (i & 31) * 4;
        *(float4*)&xs[r][c4] = *(const float4*)&x[(size_t)(mrow0 + r) * HID + c4];
    }

    float acc[4][4] = {};
    const int tr = tid >> 4;
    const int tc = tid & 15;

    for (int ph = 0; ph < 2; ++ph) {
        __syncthreads();
        for (int i = tid; i < 64 * 16; i += 256) {
            int r = i >> 4, c4 = (i & 15) * 4;
            float4 wv = *(const float4*)&W[(size_t)(n0 + r) * HID + ph * 64 + c4];
            wsT[c4 + 0][r] = wv.x;
            wsT[c4 + 1][r] = wv.y;
            wsT[c4 + 2][r] = wv.z;
            wsT[c4 + 3][r] = wv.w;
        }
        __syncthreads();
        #pragma unroll 4
        for (int k4 = 0; k4 < 16; ++k4) {
            float4 xv[4];
            #pragma unroll
            for (int i = 0; i < 4; ++i)
                xv[i] = *(const float4*)&xs[tr * 4 + i][ph * 64 + k4 * 4];
            #pragma unroll
            for (int kk = 0; kk < 4; ++kk) {
                float4 wv = *(const float4*)&wsT[k4 * 4 + kk][tc * 4];
                #pragma unroll
                for (int i = 0; i < 4; ++i) {
                    float xk = ((const float*)&xv[i])[kk];
                    acc[i][0] += xk * wv.x;
                    acc[i][1] += xk * wv.y;
                    acc[i][2] += xk * wv.z;
                    acc[i][3] += xk * wv.w;
                }
            }
        }
    }

    // SCALE * log2(e): exp(s*SCALE) == exp2(s * SCALE * log2e)
    const float scale = (p == 0) ? 0.25500544458521289f : 1.0f;
    float4 bv4 = *(const float4*)&bias[n0 + tc * 4];
    const int nbase = n0 + tc * 4;
    const int h = nbase >> 5;
    const int d = nbase & 31;
    #pragma unroll
    for (int i = 0; i < 4; ++i) {
        int m = mrow0 + tr * 4 + i;
        int c = m >> 12, s = m & 4095;
        unsigned short pk[4];
        pk[0] = f2bf((acc[i][0] + bv4.x) * scale);
        pk[1] = f2bf((acc[i][1] + bv4.y) * scale);
        pk[2] = f2bf((acc[i][2] + bv4.z) * scale);
        pk[3] = f2bf((acc[i][3] + bv4.w) * scale);
        *(uint2*)&Out[((size_t)(c * NHEAD + h) * S_LEN + s) * HDIM + d] = *(uint2*)pk;
    }
}

// ---------------------------------------------------------------------------
// Kernel 2: transpose V (C,NH,S,HD) -> Vt (C,NH,HD,S), bf16.  [validated r1/r2]
// ---------------------------------------------------------------------------
__global__ __launch_bounds__(256) void vtrans_kernel(
    const unsigned short* __restrict__ V, unsigned short* __restrict__ Vt)
{
    __shared__ unsigned short vs[64][40];
    const int tid = threadIdx.x;
    const int chh = blockIdx.y;
    const int s0 = blockIdx.x * 64;
    const size_t base = (size_t)chh * S_LEN * HDIM;
    {
        int r = tid >> 2, ch = (tid & 3) * 8;
        *(uint4*)&vs[r][ch] = *(const uint4*)&V[base + (size_t)(s0 + r) * HDIM + ch];
    }
    __syncthreads();
    {
        int dd = tid >> 3, chs = (tid & 7) * 8;
        unsigned short pk[8];
        #pragma unroll
        for (int j = 0; j < 8; ++j) pk[j] = vs[chs + j][dd];
        *(uint4*)&Vt[(size_t)chh * HDIM * S_LEN + (size_t)dd * S_LEN + s0 + chs] = *(uint4*)pk;
    }
}

// ---------------------------------------------------------------------------
// Kernel 3: attention, split-K, dual q-subtile (r1 body x r2 shell).
// Block = (32-query tile, c, split); wave = head.  No LDS, no barriers.
// p = max(ew,eps) * exp2(qk_prescaled); unnormalized partial O + denom out.
// ---------------------------------------------------------------------------
__global__ __launch_bounds__(256) void attn_kernel(
    const unsigned short* __restrict__ Q, const unsigned short* __restrict__ K,
    const unsigned short* __restrict__ Vt, const float* __restrict__ ew,
    float* __restrict__ partO, float* __restrict__ den)
{
    const int tid = threadIdx.x;
    const int w = tid >> 6;          // head
    const int lane = tid & 63;
    const int li = lane & 15;
    const int g = lane >> 4;
    const int c = blockIdx.y;
    const int qbase = blockIdx.x * 32;
    const int split = blockIdx.z;
    const int kb0 = split * KCHUNK;
    const int chh = c * NHEAD + w;

    const size_t hb = (size_t)chh * S_LEN * HDIM;
    const unsigned short* Qh = Q + hb;

    short8v qf0 = *(const short8v*)&Qh[(size_t)(qbase + li) * HDIM + g * 8];
    short8v qf1 = *(const short8v*)&Qh[(size_t)(qbase + 16 + li) * HDIM + g * 8];

    const unsigned short* kp  = K + hb + (size_t)(kb0 + li) * HDIM + g * 8;
    const unsigned short* vp0 = Vt + hb + (size_t)li * S_LEN + kb0 + g * 4;        // d = li
    const unsigned short* vp1 = vp0 + (size_t)16 * S_LEN;                          // d = 16+li
    const float* ep0 = ew + (size_t)c * S_LEN * S_LEN + (size_t)(qbase + li) * S_LEN + kb0 + g * 4;
    const float* ep1 = ep0 + (size_t)16 * S_LEN;

    float4v o00 = {}, o01 = {}, o10 = {}, o11 = {};
    float den0 = 0.f, den1 = 0.f;
    const float4v zero4 = {0.f, 0.f, 0.f, 0.f};

    #pragma unroll 2
    for (int it = 0; it < KCHUNK / 32; ++it) {
        short8v kf0 = *(const short8v*)kp;
        short8v kf1 = *(const short8v*)(kp + 512);

        union { short8v v; uint2 u2[2]; } v0, v1;
        v0.u2[0] = *(const uint2*)vp0;
        v0.u2[1] = *(const uint2*)(vp0 + 16);
        v1.u2[0] = *(const uint2*)vp1;
        v1.u2[1] = *(const uint2*)(vp1 + 16);

        float4 e00 = *(const float4*)ep0;
        float4 e01 = *(const float4*)(ep0 + 16);
        float4 e10 = *(const float4*)ep1;
        float4 e11 = *(const float4*)(ep1 + 16);

        float4v s0 = __builtin_amdgcn_mfma_f32_16x16x32_bf16(kf0, qf0, zero4, 0, 0, 0);
        float4v s1 = __builtin_amdgcn_mfma_f32_16x16x32_bf16(kf1, qf0, zero4, 0, 0, 0);
        float4v s2 = __builtin_amdgcn_mfma_f32_16x16x32_bf16(kf0, qf1, zero4, 0, 0, 0);
        float4v s3 = __builtin_amdgcn_mfma_f32_16x16x32_bf16(kf1, qf1, zero4, 0, 0, 0);

        float p0 = fmaxf(e00.x, EPSW) * exp2_asm(s0[0]);
        float p1 = fmaxf(e00.y, EPSW) * exp2_asm(s0[1]);
        float p2 = fmaxf(e00.z, EPSW) * exp2_asm(s0[2]);
        float p3 = fmaxf(e00.w, EPSW) * exp2_asm(s0[3]);
        float p4 = fmaxf(e01.x, EPSW) * exp2_asm(s1[0]);
        float p5 = fmaxf(e01.y, EPSW) * exp2_asm(s1[1]);
        float p6 = fmaxf(e01.z, EPSW) * exp2_asm(s1[2]);
        float p7 = fmaxf(e01.w, EPSW) * exp2_asm(s1[3]);
        union { short8v v; unsigned u[4]; } pu0;
        pu0.u[0] = cvt_pk_bf16(p0, p1);
        pu0.u[1] = cvt_pk_bf16(p2, p3);
        pu0.u[2] = cvt_pk_bf16(p4, p5);
        pu0.u[3] = cvt_pk_bf16(p6, p7);
        den0 += ((p0 + p1) + (p2 + p3)) + ((p4 + p5) + (p6 + p7));
        o00 = __builtin_amdgcn_mfma_f32_16x16x32_bf16(v0.v, pu0.v, o00, 0, 0, 0);
        o01 = __builtin_amdgcn_mfma_f32_16x16x32_bf16(v1.v, pu0.v, o01, 0, 0, 0);

        float r0 = fmaxf(e10.x, EPSW) * exp2_asm(s2[0]);
        float r1 = fmaxf(e10.y, EPSW) * exp2_asm(s2[1]);
        float r2 = fmaxf(e10.z, EPSW) * exp2_asm(s2[2]);
        float r3 = fmaxf(e10.w, EPSW) * exp2_asm(s2[3]);
        float r4 = fmaxf(e11.x, EPSW) * exp2_asm(s3[0]);
        float r5 = fmaxf(e11.y, EPSW) * exp2_asm(s3[1]);
        float r6 = fmaxf(e11.z, EPSW) * exp2_asm(s3[2]);
        float r7 = fmaxf(e11.w, EPSW) * exp2_asm(s3[3]);
        union { short8v v; unsigned u[4]; } pu1;
        pu1.u[0] = cvt_pk_bf16(r0, r1);
        pu1.u[1] = cvt_pk_bf16(r2, r3);
        pu1.u[2] = cvt_pk_bf16(r4, r5);
        pu1.u[3] = cvt_pk_bf16(r6, r7);
        den1 += ((r0 + r1) + (r2 + r3)) + ((r4 + r5) + (r6 + r7));
        o10 = __builtin_amdgcn_mfma_f32_16x16x32_bf16(v0.v, pu1.v, o10, 0, 0, 0);
        o11 = __builtin_amdgcn_mfma_f32_16x16x32_bf16(v1.v, pu1.v, o11, 0, 0, 0);

        kp += 1024;       // 32 keys * 32 dims
        vp0 += 32;
        vp1 += 32;
        ep0 += 32;
        ep1 += 32;
    }

    den0 += __shfl_xor(den0, 16, 64);
    den0 += __shfl_xor(den0, 32, 64);
    den1 += __shfl_xor(den1, 16, 64);
    den1 += __shfl_xor(den1, 32, 64);

    const size_t pbase = (((size_t)split * CBATCH + c) * NHEAD + w) * S_LEN + qbase;
    {
        const size_t pb = pbase + li;
        float4 o;
        o.x = o00[0]; o.y = o00[1]; o.z = o00[2]; o.w = o00[3];
        *(float4*)&partO[pb * HDIM + 0 * 16 + g * 4] = o;
        o.x = o01[0]; o.y = o01[1]; o.z = o01[2]; o.w = o01[3];
        *(float4*)&partO[pb * HDIM + 1 * 16 + g * 4] = o;
        if (g == 0) den[pb] = den0;
    }
    {
        const size_t pb = pbase + 16 + li;
        float4 o;
        o.x = o10[0]; o.y = o10[1]; o.z = o10[2]; o.w = o10[3];
        *(float4*)&partO[pb * HDIM + 0 * 16 + g * 4] = o;
        o.x = o11[0]; o.y = o11[1]; o.z = o11[2]; o.w = o11[3];
        *(float4*)&partO[pb * HDIM + 1 * 16 + g * 4] = o;
        if (g == 0) den[pb] = den1;
    }
}

// ---------------------------------------------------------------------------
// Kernel 4: combine splits -> normalized attention output (C,S,HID) fp32.
// ---------------------------------------------------------------------------
__global__ __launch_bounds__(256) void combine_kernel(
    const float* __restrict__ pO, const float* __restrict__ den,
    float* __restrict__ attnbuf)
{
    const int idx = blockIdx.x * 256 + threadIdx.x;
    const int d4 = idx & 7;
    const int q  = (idx >> 3) & (S_LEN - 1);
    const int h  = (idx >> 15) & 3;
    const int c  = idx >> 17;

    const size_t b0 = ((size_t)(0 * CBATCH + c) * NHEAD + h) * S_LEN + q;
    const size_t b1 = ((size_t)(1 * CBATCH + c) * NHEAD + h) * S_LEN + q;
    float4 a = *(const float4*)&pO[b0 * HDIM + d4 * 4];
    float4 b = *(const float4*)&pO[b1 * HDIM + d4 * 4];
    float inv = 1.0f / (den[b0] + den[b1]);
    float4 o;
    o.x = (a.x + b.x) * inv;
    o.y = (a.y + b.y) * inv;
    o.z = (a.z + b.z) * inv;
    o.w = (a.w + b.w) * inv;
    *(float4*)&attnbuf[((size_t)c * S_LEN + q) * HID + h * HDIM + d4 * 4] = o;
}

// ---------------------------------------------------------------------------
// Kernel 5: output projection. out = attnbuf @ Wo.T + bo   (all fp32)
// ---------------------------------------------------------------------------
__global__ __launch_bounds__(256) void out_proj_kernel(
    const float* __restrict__ ain, const float* __restrict__ Wo,
    const float* __restrict__ bo, float* __restrict__ out)
{
    __shared__ float xs[64][132];
    __shared__ float wsT[64][68];

    const int tid = threadIdx.x;
    const int mrow0 = blockIdx.x * 64;
    const int n0 = blockIdx.y * 64;

    for (int i = tid; i < 64 * 32; i += 256) {
        int r = i >> 5, c4 = (i & 31) * 4;
        *(float4*)&xs[r][c4] = *(const float4*)&ain[(size_t)(mrow0 + r) * HID + c4];
    }

    float acc[4][4] = {};
    const int tr = tid >> 4;
    const int tc = tid & 15;

    for (int ph = 0; ph < 2; ++ph) {
        __syncthreads();
        for (int i = tid; i < 64 * 16; i += 256) {
            int r = i >> 4, c4 = (i & 15) * 4;
            float4 wv = *(const float4*)&Wo[(size_t)(n0 + r) * HID + ph * 64 + c4];
            wsT[c4 + 0][r] = wv.x;
            wsT[c4 + 1][r] = wv.y;
            wsT[c4 + 2][r] = wv.z;
            wsT[c4 + 3][r] = wv.w;
        }
        __syncthreads();
        #pragma unroll 4
        for (int k4 = 0; k4 < 16; ++k4) {
            float4 xv[4];
            #pragma unroll
            for (int i = 0; i < 4; ++i)
                xv[i] = *(const float4*)&xs[tr * 4 + i][ph * 64 + k4 * 4];
            #pragma unroll
            for (int kk = 0; kk < 4; ++kk) {
                float4 wv = *(const float4*)&wsT[k4 * 4 + kk][tc * 4];
                #pragma unroll
                for (int i = 0; i < 4; ++i) {
                    float xk = ((const float*)&xv[i])[kk];
                    acc[i][0] += xk * wv.x;
                    acc[i][1] += xk * wv.y;
                    acc[i][2] += xk * wv.z;
                    acc[i][3] += xk * wv.w;
                }
            }
        }
    }

    float4 bv4 = *(const float4*)&bo[n0 + tc * 4];
    #pragma unroll
    for (int i = 0; i < 4; ++i) {
        int m = mrow0 + tr * 4 + i;
        float4 o;
        o.x = acc[i][0] + bv4.x;
        o.y = acc[i][1] + bv4.y;
        o.z = acc[i][2] + bv4.z;
        o.w = acc[i][3] + bv4.w;
        *(float4*)&out[(size_t)m * HID + n0 + tc * 4] = o;
    }
}

extern "C" void kernel_launch(void* const* d_in, const int* in_sizes, int n_in,
                              void* d_out, int out_size, void* d_ws, size_t ws_size,
                              hipStream_t stream) {
    const float* x  = (const float*)d_in[0];
    const float* ew = (const float*)d_in[1];
    const float* Wq = (const float*)d_in[2];
    const float* bq = (const float*)d_in[3];
    const float* Wk = (const float*)d_in[4];
    const float* bk = (const float*)d_in[5];
    const float* Wv = (const float*)d_in[6];
    const float* bv = (const float*)d_in[7];
    const float* Wo = (const float*)d_in[8];
    const float* bo = (const float*)d_in[9];
    float* out = (float*)d_out;

    char* ws = (char*)d_ws;
    const size_t QSZ = (size_t)CBATCH * NHEAD * S_LEN * HDIM * sizeof(unsigned short); // 4 MiB
    unsigned short* Qw  = (unsigned short*)(ws);
    unsigned short* Kw  = (unsigned short*)(ws + QSZ);
    unsigned short* Vtw = (unsigned short*)(ws + 2 * QSZ);
    unsigned short* Vw  = (unsigned short*)(ws + 3 * QSZ);
    float* partO = (float*)(ws + 3 * QSZ);           // overlaps dead Vw
    float* den   = (float*)(ws + 3 * QSZ + (size_t)NSPLIT * CBATCH * NHEAD * S_LEN * HDIM * sizeof(float));
    float* attnbuf = (float*)(ws);                    // overlaps dead Qw/Kw

    qkv_proj_kernel<<<dim3(256, 2, 3), 256, 0, stream>>>(x, Wq, bq, Wk, bk, Wv, bv, Qw, Kw, Vw);
    vtrans_kernel<<<dim3(S_LEN / 64, CBATCH * NHEAD), 256, 0, stream>>>(Vw, Vtw);
    attn_kernel<<<dim3(S_LEN / 32, CBATCH, NSPLIT), 256, 0, stream>>>(Qw, Kw, Vtw, ew, partO, den);
    combine_kernel<<<dim3((CBATCH * S_LEN * HID / 4) / 256), 256, 0, stream>>>(partO, den, attnbuf);
    out_proj_kernel<<<dim3(256, 2), 256, 0, stream>>>(attnbuf, Wo, bo, out);
}